// Round 7
// baseline (208.760 us; speedup 1.0000x reference)
//
#include <hip/hip_runtime.h>

#define RAD 6
#define KS 13
#define DIM 192
#define CH 3
#define W4C 48                 // float4 per row
#define PLANE4 (DIM * W4C)     // f4 per (h,w) plane = 9216
#define VOL4 (DIM * PLANE4)    // f4 per channel
#define VOL (DIM * DIM * DIM)
#define TOTAL (CH * VOL)       // 21,233,664 floats

// ---------------------------------------------------------------------------
// Pass 1: fused W-conv + H-conv, TWO phases only.
// Phase 1: each thread does 5 overlapping aligned b128 GLOBAL loads (L1/L2
// absorb the overlap; unique bytes unchanged), W-convolves in registers, and
// writes the convolved f4 straight to LDS. No stage-A LDS reads, no
// write-back, one barrier total.
// Phase 2: H-conv via 13-deep register sliding window over LDS; store.
// Tile: 44 h-rows (h0-6 .. h0+37) x full w = 2112 f4 = 33 KB -> 4 blocks/CU.
// g1 extraction folded in (13 threads -> LDS broadcast): no separate launch.
// Grid: 3c * 192d * 6ht = 3456 blocks, 192 threads.
// ---------------------------------------------------------------------------
#define HT1 32
#define HL1 44
#define NT1 192
#define NLD1 (HL1 * W4C)       // 2112 f4

__global__ __launch_bounds__(NT1) void conv_wh3(const float* __restrict__ in,
                                                float* __restrict__ out,
                                                const float* __restrict__ wk) {
    __shared__ float4 tile[NLD1];
    __shared__ float gS[KS];
    const int bid = blockIdx.x;
    const int ht = bid % 6;
    const int d = (bid / 6) % DIM;
    const int c = bid / (6 * DIM);
    const int h0 = ht * HT1;
    const int t = threadIdx.x;

    // g1[i] = row-sum of w over (j,k): g3=g1 x g1 x g1 with sum(g1)=1.
    if (t < KS) {
        float s = 0.f;
        for (int j = 0; j < KS * KS; ++j) s += wk[t * KS * KS + j];
        gS[t] = s;
    }
    __syncthreads();

    float g[KS];
#pragma unroll
    for (int k = 0; k < KS; ++k) g[k] = gS[k];

    const float4* in4 = (const float4*)in;
    float4* out4 = (float4*)out;
    const size_t plane = (size_t)c * VOL4 + (size_t)d * PLANE4;
    const float4 z4 = make_float4(0.f, 0.f, 0.f, 0.f);

    // ---- phase 1: load + W-conv straight into LDS (11 f4/thread exact) ----
#pragma unroll
    for (int i = 0; i < 11; ++i) {
        int idx = t + i * NT1;
        int row = idx / W4C, w4 = idx % W4C;
        int h = h0 - RAD + row;
        int hc = min(max(h, 0), DIM - 1);              // unconditional loads
        const float4* rp = in4 + plane + (size_t)hc * W4C;
        float f[20];
#pragma unroll
        for (int b = 0; b < 5; ++b) {
            int j = min(max(w4 + b - 2, 0), W4C - 1);  // clamp; OOB taps zeroed below
            float4 v = rp[j];
            f[4 * b + 0] = v.x; f[4 * b + 1] = v.y;
            f[4 * b + 2] = v.z; f[4 * b + 3] = v.w;
        }
        int w0 = w4 * 4;
#pragma unroll
        for (int j = 0; j < 20; ++j) {
            int ww = w0 - 8 + j;
            if (ww < 0 || ww >= DIM) f[j] = 0.f;
        }
        float4 o = z4;
#pragma unroll
        for (int k = 0; k < KS; ++k) {
            o.x += g[k] * f[k + 2];
            o.y += g[k] * f[k + 3];
            o.z += g[k] * f[k + 4];
            o.w += g[k] * f[k + 5];
        }
        if (h < 0 || h >= DIM) o = z4;                 // zero-pad halo rows
        tile[idx] = o;
    }
    __syncthreads();

    // ---- phase 2: H-conv. thread = (w4, rg); 4 rgs x 8 output rows each ----
    // output h = h0+i needs tile rows i .. i+12 (tile row r <-> h = h0-6+r).
    const int w4 = t % W4C;
    const int rg = t / W4C;
    const int i0 = rg * 8;
    float4 buf[KS];
#pragma unroll
    for (int j = 0; j < KS; ++j) buf[j] = tile[(i0 + j) * W4C + w4];

#pragma unroll
    for (int ii = 0; ii < 8; ++ii) {
        float4 a = z4;
#pragma unroll
        for (int j = 0; j < KS; ++j) {
            const float4 v = buf[(ii + j) % KS];
            float gw = g[j];
            a.x += gw * v.x; a.y += gw * v.y; a.z += gw * v.z; a.w += gw * v.w;
        }
        out4[plane + (size_t)(h0 + i0 + ii) * W4C + w4] = a;
        if (ii < 7) buf[ii % KS] = tile[(i0 + ii + KS) * W4C + w4];  // max row 43 < 44
    }
}

// ---------------------------------------------------------------------------
// Pass 2: D-conv. Full-depth slab, w-chunk of 8 f4 at fixed (c,h).
// LDS = 192*8 f4 = 24.6 KB -> 6 blocks/CU. Load: 6 exact independent
// b128/thread (128 B contiguous chunks at plane stride). Compute: 32 segs x
// 6 outputs via register sliding window (full axis resident, zero-pad ends).
// All b128 LDS patterns verified at the 8-clk structural floor (no padding
// needed). g1 folded in. Grid: 3c * 192h * 6wt = 3456 blocks.
// ---------------------------------------------------------------------------
__global__ __launch_bounds__(256) void conv_d8(const float* __restrict__ in,
                                               float* __restrict__ out,
                                               const float* __restrict__ wk) {
    __shared__ float4 tile[DIM * 8];
    __shared__ float gS[KS];
    const int bid = blockIdx.x;
    const int wt = bid % 6;
    const int h = (bid / 6) % DIM;
    const int c = bid / (6 * DIM);
    const int t = threadIdx.x;

    if (t < KS) {
        float s = 0.f;
        for (int j = 0; j < KS * KS; ++j) s += wk[t * KS * KS + j];
        gS[t] = s;
    }

    const float4* in4 = (const float4*)in;
    float4* out4 = (float4*)out;
    const size_t base4 = (size_t)c * VOL4 + (size_t)h * W4C + wt * 8;
    const float4 z4 = make_float4(0.f, 0.f, 0.f, 0.f);

#pragma unroll
    for (int i = 0; i < 6; ++i) {
        int idx = t + i * 256;
        int dd = idx / 8, w = idx % 8;
        tile[idx] = in4[base4 + (size_t)dd * PLANE4 + w];   // exactly-once
    }
    __syncthreads();

    float g[KS];
#pragma unroll
    for (int k = 0; k < KS; ++k) g[k] = gS[k];

    const int w = t % 8;
    const int seg = t / 8;       // 32 segs x 6 outputs
    const int d0 = seg * 6;

    float4 buf[KS];
#pragma unroll
    for (int j = 0; j < KS; ++j) {
        int p = d0 - RAD + j;
        buf[j] = (p >= 0 && p < DIM) ? tile[p * 8 + w] : z4;
    }

#pragma unroll
    for (int i = 0; i < 6; ++i) {
        float4 a = z4;
#pragma unroll
        for (int j = 0; j < KS; ++j) {
            const float4 v = buf[(i + j) % KS];
            float gw = g[j];
            a.x += gw * v.x; a.y += gw * v.y; a.z += gw * v.z; a.w += gw * v.w;
        }
        out4[base4 + (size_t)(d0 + i) * PLANE4 + w] = a;
        if (i < 5) {
            int p = d0 + i + RAD + 1;
            buf[i % KS] = (p < DIM) ? tile[p * 8 + w] : z4;
        }
    }
}

// Fallback: direct 2197-tap depthwise conv (only if ws_size is too small).
__global__ void naive_conv3d_kernel(const float* __restrict__ x, const float* __restrict__ w,
                                    float* __restrict__ out, int total) {
    int n = blockIdx.x * blockDim.x + threadIdx.x;
    if (n >= total) return;
    int wp = n % DIM;
    int h = (n / DIM) % DIM;
    int d = (n / (DIM * DIM)) % DIM;
    int c = n / (DIM * DIM * DIM);
    const float* wc = w + c * KS * KS * KS;
    const float* xc = x + (size_t)c * DIM * DIM * DIM;
    float acc = 0.f;
    for (int kd = 0; kd < KS; ++kd) {
        int dd = d + kd - RAD;
        if (dd < 0 || dd >= DIM) continue;
        for (int kh = 0; kh < KS; ++kh) {
            int hh = h + kh - RAD;
            if (hh < 0 || hh >= DIM) continue;
            for (int kw = 0; kw < KS; ++kw) {
                int ww = wp + kw - RAD;
                if (ww < 0 || ww >= DIM) continue;
                acc += wc[(kd * KS + kh) * KS + kw] * xc[((size_t)dd * DIM + hh) * DIM + ww];
            }
        }
    }
    out[n] = acc;
}

extern "C" void kernel_launch(void* const* d_in, const int* in_sizes, int n_in,
                              void* d_out, int out_size, void* d_ws, size_t ws_size,
                              hipStream_t stream) {
    const float* x = (const float*)d_in[0];
    const float* w = (const float*)d_in[1];
    float* out = (float*)d_out;

    const size_t inter_bytes = (size_t)TOTAL * sizeof(float);  // ~85 MB

    if (ws_size >= inter_bytes) {
        float* inter = (float*)d_ws;

        // Pass 1: fused W+H conv, x -> inter. 3456 blocks, 33 KB LDS.
        conv_wh3<<<CH * DIM * 6, NT1, 0, stream>>>(x, inter, w);

        // Pass 2: D conv, inter -> out. 3456 blocks, 24.6 KB LDS.
        conv_d8<<<CH * DIM * 6, 256, 0, stream>>>(inter, out, w);
    } else {
        const int threads = 256;
        const int blocks = (TOTAL + threads - 1) / threads;
        naive_conv3d_kernel<<<blocks, threads, 0, stream>>>(x, w, out, TOTAL);
    }
}